// Round 9
// baseline (204.404 us; speedup 1.0000x reference)
//
#include <hip/hip_runtime.h>
#include <math.h>

// CRF loss: B=256, L=256, T=50. ONE WAVE per batch element, barrier-free scan.
//
// R9 = R8's verified MFMA recurrence with the per-step cost stripped down:
//   v'[to] = (sum_f v[f] * E2[f][to]) * eh_l[to],  E2 = exp2(trans/ln2) const bf16.
// K-permuted pairing (verified R8): A-slot j=2r(+1) at quad q, chunk c carries
// tags (16c+4q+r, +32). Lane n holds v for tags {n, n+16, n+32, n+48} (quad-replicated).
// Per step: pack 2 ints -> LDS write (lane-strided, 2-way free) -> 2x ds_read_b128
// (quad-broadcast, conflict-free) -> 8 independent MFMAs -> 4 add, 4 mul, 4 cndmask.
// eh table is PRE-EXP2'd into LDS once (no exp2 in loop). Renorm every step but
// fully off-path: ehrr = eh*rr and velse = v*rr computed during the DS/MFMA wait.
// State: alpha = v * 2^S, S += log2(v_prev[0]); |log2 v| <= ~45 -> fp32 safe.

#define TAGS 50
#define LEN 256
#define INV_LN2 1.4426950408889634f
#define LN2 0.6931471805599453f

typedef __attribute__((ext_vector_type(8))) short bf16x8;
typedef __attribute__((ext_vector_type(4))) float f32x4;

#if __has_builtin(__builtin_amdgcn_exp2f)
#define EXP2F(x) __builtin_amdgcn_exp2f(x)
#else
#define EXP2F(x) exp2f(x)
#endif
#if __has_builtin(__builtin_amdgcn_logf)
#define LOG2F(x) __builtin_amdgcn_logf(x)
#else
#define LOG2F(x) log2f(x)
#endif
#if __has_builtin(__builtin_amdgcn_rcpf)
#define RCPF(x) __builtin_amdgcn_rcpf(x)
#else
#define RCPF(x) (1.0f / (x))
#endif

__device__ __forceinline__ float readlane_f(float v, int srclane) {
  return __builtin_bit_cast(float,
      __builtin_amdgcn_readlane(__builtin_bit_cast(int, v), srclane));
}

// Pack two fp32 into one VGPR as (bf16(hi) << 16) | bf16(lo), round-half-up.
__device__ __forceinline__ int bf16pair(float lo, float hi) {
  unsigned lb = (__builtin_bit_cast(unsigned, lo) + 0x8000u) >> 16;
  unsigned hb = (__builtin_bit_cast(unsigned, hi) + 0x8000u) & 0xFFFF0000u;
  return (int)(hb | lb);
}

__global__ __launch_bounds__(64) void crf_fwd_kernel(
    const float* __restrict__ feats,   // (B, L, T)
    const float* __restrict__ trans,   // (T, T)
    const int*   __restrict__ tags,    // (B, L)
    const int*   __restrict__ mask,    // (B, L)
    float*       __restrict__ out)     // (B,)
{
  const int b    = blockIdx.x;
  const int lane = threadIdx.x;
  const int q    = lane >> 4;                        // MFMA quad
  const int n    = lane & 15;                        // MFMA col within tile

  __shared__ __align__(16) float eh_lds[LEN * 64];   // exp2(emit/ln2), pads = 0 (64 KB)
  __shared__ __align__(16) int   move_lds[128];      // P0 at [0..63], P1 at [64..127]
  __shared__ int mask_lds[LEN];

  const float* fb = feats + (size_t)b * (LEN * TAGS);
  const int*   tb = tags + b * LEN;
  const int*   mb = mask + b * LEN;

  // Gold-score tags into registers (latency overlaps preload).
  int tg_c[4], tg_p[4];
#pragma unroll
  for (int k = 0; k < 4; ++k) {
    const int p = lane + 64 * k;
    tg_c[k] = tb[p];
    tg_p[k] = (p >= 1) ? tb[p - 1] : 0;
  }

  // ---- One-time: pre-exp2'd emit table (pads 0) + mask ----
  for (int i = lane; i < LEN * 64; i += 64) {
    const int l = i >> 6, to = i & 63;
    eh_lds[i] = (to < TAGS) ? EXP2F(fb[l * TAGS + to] * INV_LN2) : 0.0f;
  }
  for (int i = lane; i < LEN; i += 64) mask_lds[i] = mb[i];

  // ---- Constant B-frags (verified R8 K-permutation):
  //      slot j=2r(+1) at quad q, chunk c carries tag 16c+4q+r (+32); col 16t+n.
  union U8 { int i[4]; bf16x8 v; };
  U8 Bfr[4][2];
#pragma unroll
  for (int t = 0; t < 4; ++t)
#pragma unroll
    for (int c = 0; c < 2; ++c)
#pragma unroll
      for (int r = 0; r < 4; ++r) {
        const int col = 16 * t + n;
        const int tag0 = 16 * c + 4 * q + r;
        const int tag1 = tag0 + 32;
        const float e0 = (tag0 < TAGS && col < TAGS)
            ? EXP2F(trans[tag0 * TAGS + col] * INV_LN2) : 0.0f;
        const float e1 = (tag1 < TAGS && col < TAGS)
            ? EXP2F(trans[tag1 * TAGS + col] * INV_LN2) : 0.0f;
        Bfr[t][c].i[r] = bf16pair(e0, e1);
      }

  __syncthreads();                                   // single wave: waitcnt only

  // ---- Init: v[t] = eh0[tag]/eh0[0]; S = log2(eh0[0]) = e0[0]. ----
  const float piv0 = eh_lds[0];                      // > 0, wave-uniform
  const float rr0 = RCPF(piv0);
  float v[4];
#pragma unroll
  for (int t = 0; t < 4; ++t) v[t] = eh_lds[n + 16 * t] * rr0;  // pads: 0
  float S = LOG2F(piv0);

  const f32x4 zero4 = {0.0f, 0.0f, 0.0f, 0.0f};

  for (int l = 1; l < LEN; ++l) {
    // ---- Pack pairs (local by construction) and stage through LDS ----
    const int P0 = bf16pair(v[0], v[2]);             // (v[n],    v[n+32])
    const int P1 = bf16pair(v[1], v[3]);             // (v[n+16], v[n+48])
    move_lds[lane] = P0;
    move_lds[64 + lane] = P1;
    __builtin_amdgcn_wave_barrier();                 // keep write before read

    // A-frags: slot pairs from lanes 4q+r -> one b128 per chunk (broadcast reads).
    U8 A0, A1;
    *(f32x4*)&A0 = *(const f32x4*)&move_lds[4 * q];
    *(f32x4*)&A1 = *(const f32x4*)&move_lds[64 + 4 * q];

    // ---- Off-path while DS/MFMA in flight: renorm + eh + mask ----
    const float cc = readlane_f(v[0], 0);            // v_prev[tag 0] > 0
    const float rr = RCPF(cc);
    float ehrr[4], velse[4];
#pragma unroll
    for (int t = 0; t < 4; ++t) {
      ehrr[t] = eh_lds[l * 64 + n + 16 * t] * rr;    // pads: 0
      velse[t] = v[t] * rr;
    }
    const int m_cur = mask_lds[l];
    S += LOG2F(cc);

    // ---- 8 independent MFMAs (4 n-tiles x 2 k-chunks) ----
    f32x4 d0 = __builtin_amdgcn_mfma_f32_16x16x32_bf16(A0.v, Bfr[0][0].v, zero4, 0, 0, 0);
    f32x4 d1 = __builtin_amdgcn_mfma_f32_16x16x32_bf16(A0.v, Bfr[1][0].v, zero4, 0, 0, 0);
    f32x4 d2 = __builtin_amdgcn_mfma_f32_16x16x32_bf16(A0.v, Bfr[2][0].v, zero4, 0, 0, 0);
    f32x4 d3 = __builtin_amdgcn_mfma_f32_16x16x32_bf16(A0.v, Bfr[3][0].v, zero4, 0, 0, 0);
    f32x4 g0 = __builtin_amdgcn_mfma_f32_16x16x32_bf16(A1.v, Bfr[0][1].v, zero4, 0, 0, 0);
    f32x4 g1 = __builtin_amdgcn_mfma_f32_16x16x32_bf16(A1.v, Bfr[1][1].v, zero4, 0, 0, 0);
    f32x4 g2 = __builtin_amdgcn_mfma_f32_16x16x32_bf16(A1.v, Bfr[2][1].v, zero4, 0, 0, 0);
    f32x4 g3 = __builtin_amdgcn_mfma_f32_16x16x32_bf16(A1.v, Bfr[3][1].v, zero4, 0, 0, 0);

    // ---- On-path tail: add, scale(+renorm), mask-select ----
    const float c0 = (d0[0] + g0[0]) * ehrr[0];
    const float c1 = (d1[0] + g1[0]) * ehrr[1];
    const float c2 = (d2[0] + g2[0]) * ehrr[2];
    const float c3 = (d3[0] + g3[0]) * ehrr[3];
    v[0] = (m_cur > 0) ? c0 : velse[0];
    v[1] = (m_cur > 0) ? c1 : velse[1];
    v[2] = (m_cur > 0) ? c2 : velse[2];
    v[3] = (m_cur > 0) ? c3 : velse[3];
  }

  // ---- Final logsumexp: pads are 0; quads are replicas -> reduce 16 cols ----
  float vsum = (v[0] + v[1]) + (v[2] + v[3]);
#pragma unroll
  for (int off = 8; off; off >>= 1) vsum += __shfl_xor(vsum, off, 64);
  // lanes with n==0 now hold the full sum over all tags.

  // ---- Gold score (global reads, one-time): positions lane, +64, +128, +192 ----
  float gp = 0.0f;
#pragma unroll
  for (int k = 0; k < 4; ++k) {
    const int p = lane + 64 * k;
    if (mask_lds[p] > 0) {
      float vv = fb[p * TAGS + tg_c[k]];
      if (p >= 1) vv += trans[tg_p[k] * TAGS + tg_c[k]];
      gp += vv;
    }
  }
#pragma unroll
  for (int off = 32; off; off >>= 1) gp += __shfl_xor(gp, off, 64);

  if (lane == 0) {
    const float all_path = LN2 * (S + LOG2F(vsum));
    out[b] = all_path - gp;
  }
}

extern "C" void kernel_launch(void* const* d_in, const int* in_sizes, int n_in,
                              void* d_out, int out_size, void* d_ws, size_t ws_size,
                              hipStream_t stream) {
  const float* feats = (const float*)d_in[0];
  const float* trans = (const float*)d_in[1];
  const int*   tags  = (const int*)d_in[2];
  const int*   mask  = (const int*)d_in[3];
  float* out = (float*)d_out;

  const int B = out_size;  // 256
  crf_fwd_kernel<<<B, 64, 0, stream>>>(feats, trans, tags, mask, out);
}

// Round 10
// 103.948 us; speedup vs baseline: 1.9664x; 1.9664x over previous
//
#include <hip/hip_runtime.h>
#include <math.h>

// CRF loss: B=256, L=256, T=50.
// R10: forward/backward SPLIT to halve the serial depth (255 -> 128 steps).
//   normalizer = v0 . M1..M255 . 1,  M_l = mask_l ? E2*diag(eh_l) : I.
//   K1 (512 blocks, 1 wave each): blocks 0..255   fwd:  u = v0 . M1..M127
//                                 blocks 256..511 bwd:  w = M128..M255 . 1
//   K2 (256 blocks): out = ln2*(Sf+Sb+log2(sum u.w)) - gold.
// Loop machinery is R8-verbatim (verified, absmax 8.0): K-permuted bf16 pairs,
// 8 ds_bpermute crossing, 8 independent mfma_f32_16x16x32_bf16, stale-pivot
// renorm (alpha = v * 2^S). Bwd uses the SAME code with transposed B-frags
// (contraction over "to") and eh applied before the pack (x = eh .* w).

#define TAGS 50
#define LEN 256
#define NB 256
#define HALF 128
#define INV_LN2 1.4426950408889634f
#define LN2 0.6931471805599453f

typedef __attribute__((ext_vector_type(8))) short bf16x8;
typedef __attribute__((ext_vector_type(4))) float f32x4;

#if __has_builtin(__builtin_amdgcn_exp2f)
#define EXP2F(x) __builtin_amdgcn_exp2f(x)
#else
#define EXP2F(x) exp2f(x)
#endif
#if __has_builtin(__builtin_amdgcn_logf)
#define LOG2F(x) __builtin_amdgcn_logf(x)
#else
#define LOG2F(x) log2f(x)
#endif
#if __has_builtin(__builtin_amdgcn_rcpf)
#define RCPF(x) __builtin_amdgcn_rcpf(x)
#else
#define RCPF(x) (1.0f / (x))
#endif

__device__ __forceinline__ float readlane_f(float v, int srclane) {
  return __builtin_bit_cast(float,
      __builtin_amdgcn_readlane(__builtin_bit_cast(int, v), srclane));
}

// Pack two fp32 into one VGPR as (bf16(hi) << 16) | bf16(lo), round-half-up.
__device__ __forceinline__ int bf16pair(float lo, float hi) {
  unsigned lb = (__builtin_bit_cast(unsigned, lo) + 0x8000u) >> 16;
  unsigned hb = (__builtin_bit_cast(unsigned, hi) + 0x8000u) & 0xFFFF0000u;
  return (int)(hb | lb);
}

union U8 { int i[4]; bf16x8 v; };

// ws layout (floats): u[NB][64] | w[NB][64] | Sf[NB] | Sb[NB]
#define WS_U(b)  ((b) * 64)
#define WS_W(b)  ((NB + (b)) * 64)
#define WS_SF(b) (2 * NB * 64 + (b))
#define WS_SB(b) (2 * NB * 64 + NB + (b))

__global__ __launch_bounds__(64) void crf_scan_kernel(
    const float* __restrict__ feats,   // (B, L, T)
    const float* __restrict__ trans,   // (T, T)
    const int*   __restrict__ mask,    // (B, L)
    float*       __restrict__ ws)
{
  const int bid    = blockIdx.x;
  const bool is_fwd = bid < NB;
  const int b      = is_fwd ? bid : bid - NB;
  const int lane   = threadIdx.x;
  const int q      = lane >> 4;
  const int n      = lane & 15;

  __shared__ __align__(16) float fl[HALF * TAGS]; // this half's emits, prescaled 1/ln2
  __shared__ int ml[HALF];

  const int base_l = is_fwd ? 0 : HALF;
  const float* fb = feats + ((size_t)b * LEN + base_l) * TAGS;
  const int*   mb = mask + b * LEN + base_l;

  // ---- Preload (proven float4 pattern; 1600 float4 = 25 iters/lane) ----
  {
    const float4* fv = (const float4*)fb;
    for (int i = lane; i < (HALF * TAGS) / 4; i += 64) {
      float4 v4 = fv[i];
      v4.x *= INV_LN2; v4.y *= INV_LN2; v4.z *= INV_LN2; v4.w *= INV_LN2;
      *(float4*)&fl[i * 4] = v4;
    }
    for (int i = lane; i < HALF; i += 64) ml[i] = mb[i];
  }

  // Lane's 4 tags (tile t -> tag n+16t), clamped for pads.
  int tcl[4], vld[4];
#pragma unroll
  for (int t = 0; t < 4; ++t) {
    const int tg = n + 16 * t;
    vld[t] = tg < TAGS;
    tcl[t] = vld[t] ? tg : (TAGS - 1);
  }

  // ---- Constant B-frags (R8 K-permutation). fwd: value E2[tagK][col];
  //      bwd: contraction over "to" -> value E2[col][tagK] (transposed). ----
  U8 Bfr[4][2];
#pragma unroll
  for (int t = 0; t < 4; ++t)
#pragma unroll
    for (int c = 0; c < 2; ++c)
#pragma unroll
      for (int r = 0; r < 4; ++r) {
        const int col = 16 * t + n;
        const int tag0 = 16 * c + 4 * q + r;
        const int tag1 = tag0 + 32;
        float e0 = 0.0f, e1 = 0.0f;
        if (col < TAGS) {
          if (tag0 < TAGS)
            e0 = EXP2F((is_fwd ? trans[tag0 * TAGS + col]
                               : trans[col * TAGS + tag0]) * INV_LN2);
          if (tag1 < TAGS)
            e1 = EXP2F((is_fwd ? trans[tag1 * TAGS + col]
                               : trans[col * TAGS + tag1]) * INV_LN2);
        }
        Bfr[t][c].i[r] = bf16pair(e0, e1);
      }

  int addr[4];
#pragma unroll
  for (int r = 0; r < 4; ++r) addr[r] = (4 * q + r) * 4;

  __syncthreads();                                  // single wave: waitcnt only

  const f32x4 zero4 = {0.0f, 0.0f, 0.0f, 0.0f};
  float v[4], S;

  if (is_fwd) {
    // ---- Forward: u = v0 . M1..M127 (127 steps) ----
    const float c0 = fl[0];
#pragma unroll
    for (int t = 0; t < 4; ++t) v[t] = vld[t] ? EXP2F(fl[tcl[t]] - c0) : 0.0f;
    S = c0;

    float eh[4];
#pragma unroll
    for (int t = 0; t < 4; ++t) eh[t] = EXP2F(fl[TAGS + tcl[t]]);
    int m_nxt = ml[1];

    for (int l = 1; l < HALF; ++l) {
      const int m_cur = m_nxt;
      const int ln = (l + 1 < HALF) ? (l + 1) : (HALF - 1);

      const int P0 = bf16pair(v[0], v[2]);
      const int P1 = bf16pair(v[1], v[3]);
      const float cc = readlane_f(v[0], 0);
      const float rr = RCPF(cc);

      U8 A0, A1;
#pragma unroll
      for (int r = 0; r < 4; ++r) {
        A0.i[r] = __builtin_amdgcn_ds_bpermute(addr[r], P0);
        A1.i[r] = __builtin_amdgcn_ds_bpermute(addr[r], P1);
      }

      f32x4 d0 = __builtin_amdgcn_mfma_f32_16x16x32_bf16(A0.v, Bfr[0][0].v, zero4, 0, 0, 0);
      f32x4 d1 = __builtin_amdgcn_mfma_f32_16x16x32_bf16(A0.v, Bfr[1][0].v, zero4, 0, 0, 0);
      f32x4 d2 = __builtin_amdgcn_mfma_f32_16x16x32_bf16(A0.v, Bfr[2][0].v, zero4, 0, 0, 0);
      f32x4 d3 = __builtin_amdgcn_mfma_f32_16x16x32_bf16(A0.v, Bfr[3][0].v, zero4, 0, 0, 0);
      f32x4 g0 = __builtin_amdgcn_mfma_f32_16x16x32_bf16(A1.v, Bfr[0][1].v, zero4, 0, 0, 0);
      f32x4 g1 = __builtin_amdgcn_mfma_f32_16x16x32_bf16(A1.v, Bfr[1][1].v, zero4, 0, 0, 0);
      f32x4 g2 = __builtin_amdgcn_mfma_f32_16x16x32_bf16(A1.v, Bfr[2][1].v, zero4, 0, 0, 0);
      f32x4 g3 = __builtin_amdgcn_mfma_f32_16x16x32_bf16(A1.v, Bfr[3][1].v, zero4, 0, 0, 0);

      float ehn[4];
#pragma unroll
      for (int t = 0; t < 4; ++t) ehn[t] = fl[ln * TAGS + tcl[t]];
      const int m_n2 = ml[ln];

      v[0] = ((m_cur > 0) ? (d0[0] + g0[0]) * eh[0] : v[0]) * rr;
      v[1] = ((m_cur > 0) ? (d1[0] + g1[0]) * eh[1] : v[1]) * rr;
      v[2] = ((m_cur > 0) ? (d2[0] + g2[0]) * eh[2] : v[2]) * rr;
      v[3] = ((m_cur > 0) ? (d3[0] + g3[0]) * eh[3] : v[3]) * rr;
      S += LOG2F(cc);
#pragma unroll
      for (int t = 0; t < 4; ++t) eh[t] = EXP2F(ehn[t]);
      m_nxt = m_n2;
    }

    if (lane < 16) {
#pragma unroll
      for (int t = 0; t < 4; ++t) ws[WS_U(b) + n + 16 * t] = v[t];
    }
    if (lane == 0) ws[WS_SF(b)] = S;
  } else {
    // ---- Backward: w = M128..M255 . 1 (128 steps, l_local 127..0) ----
#pragma unroll
    for (int t = 0; t < 4; ++t) v[t] = vld[t] ? 1.0f : 0.0f;
    S = 0.0f;

    float eh[4];
#pragma unroll
    for (int t = 0; t < 4; ++t) eh[t] = EXP2F(fl[(HALF - 1) * TAGS + tcl[t]]);
    int m_nxt = ml[HALF - 1];

    for (int l = HALF - 1; l >= 0; --l) {
      const int m_cur = m_nxt;
      const int ln = (l > 0) ? (l - 1) : 0;

      // x = eh_l .* w (pads: w = 0)
      const float x0 = v[0] * eh[0];
      const float x1 = v[1] * eh[1];
      const float x2 = v[2] * eh[2];
      const float x3 = v[3] * eh[3];
      const int P0 = bf16pair(x0, x2);
      const int P1 = bf16pair(x1, x3);
      const float cc = readlane_f(v[0], 0);
      const float rr = RCPF(cc);

      U8 A0, A1;
#pragma unroll
      for (int r = 0; r < 4; ++r) {
        A0.i[r] = __builtin_amdgcn_ds_bpermute(addr[r], P0);
        A1.i[r] = __builtin_amdgcn_ds_bpermute(addr[r], P1);
      }

      f32x4 d0 = __builtin_amdgcn_mfma_f32_16x16x32_bf16(A0.v, Bfr[0][0].v, zero4, 0, 0, 0);
      f32x4 d1 = __builtin_amdgcn_mfma_f32_16x16x32_bf16(A0.v, Bfr[1][0].v, zero4, 0, 0, 0);
      f32x4 d2 = __builtin_amdgcn_mfma_f32_16x16x32_bf16(A0.v, Bfr[2][0].v, zero4, 0, 0, 0);
      f32x4 d3 = __builtin_amdgcn_mfma_f32_16x16x32_bf16(A0.v, Bfr[3][0].v, zero4, 0, 0, 0);
      f32x4 g0 = __builtin_amdgcn_mfma_f32_16x16x32_bf16(A1.v, Bfr[0][1].v, zero4, 0, 0, 0);
      f32x4 g1 = __builtin_amdgcn_mfma_f32_16x16x32_bf16(A1.v, Bfr[1][1].v, zero4, 0, 0, 0);
      f32x4 g2 = __builtin_amdgcn_mfma_f32_16x16x32_bf16(A1.v, Bfr[2][1].v, zero4, 0, 0, 0);
      f32x4 g3 = __builtin_amdgcn_mfma_f32_16x16x32_bf16(A1.v, Bfr[3][1].v, zero4, 0, 0, 0);

      float ehn[4];
#pragma unroll
      for (int t = 0; t < 4; ++t) ehn[t] = fl[ln * TAGS + tcl[t]];
      const int m_n2 = ml[ln];

      v[0] = ((m_cur > 0) ? (d0[0] + g0[0]) : v[0]) * rr;
      v[1] = ((m_cur > 0) ? (d1[0] + g1[0]) : v[1]) * rr;
      v[2] = ((m_cur > 0) ? (d2[0] + g2[0]) : v[2]) * rr;
      v[3] = ((m_cur > 0) ? (d3[0] + g3[0]) : v[3]) * rr;
      S += LOG2F(cc);
#pragma unroll
      for (int t = 0; t < 4; ++t) eh[t] = EXP2F(ehn[t]);
      m_nxt = m_n2;
    }

    if (lane < 16) {
#pragma unroll
      for (int t = 0; t < 4; ++t) ws[WS_W(b) + n + 16 * t] = v[t];
    }
    if (lane == 0) ws[WS_SB(b)] = S;
  }
}

__global__ __launch_bounds__(64) void crf_combine_kernel(
    const float* __restrict__ feats,   // (B, L, T)
    const float* __restrict__ trans,   // (T, T)
    const int*   __restrict__ tags,    // (B, L)
    const int*   __restrict__ mask,    // (B, L)
    const float* __restrict__ ws,
    float*       __restrict__ out)     // (B,)
{
  const int b = blockIdx.x;
  const int lane = threadIdx.x;

  // normalizer = ln2 * (Sf + Sb + log2(sum_tag u*w))   (pads are 0)
  float s = ws[WS_U(b) + lane] * ws[WS_W(b) + lane];
#pragma unroll
  for (int off = 32; off; off >>= 1) s += __shfl_xor(s, off, 64);

  // gold score: lane handles positions lane, +64, +128, +192
  const float* fb = feats + (size_t)b * (LEN * TAGS);
  const int*   tb = tags + b * LEN;
  const int*   mb = mask + b * LEN;
  float gp = 0.0f;
#pragma unroll
  for (int k = 0; k < 4; ++k) {
    const int p = lane + 64 * k;
    const int tg = tb[p];
    if (mb[p] > 0) {
      float vv = fb[p * TAGS + tg];
      if (p >= 1) vv += trans[tb[p - 1] * TAGS + tg];
      gp += vv;
    }
  }
#pragma unroll
  for (int off = 32; off; off >>= 1) gp += __shfl_xor(gp, off, 64);

  if (lane == 0) {
    const float Sf = ws[WS_SF(b)];
    const float Sb = ws[WS_SB(b)];
    out[b] = LN2 * (Sf + Sb + LOG2F(s)) - gp;
  }
}

extern "C" void kernel_launch(void* const* d_in, const int* in_sizes, int n_in,
                              void* d_out, int out_size, void* d_ws, size_t ws_size,
                              hipStream_t stream) {
  const float* feats = (const float*)d_in[0];
  const float* trans = (const float*)d_in[1];
  const int*   tags  = (const int*)d_in[2];
  const int*   mask  = (const int*)d_in[3];
  float* out = (float*)d_out;
  float* ws  = (float*)d_ws;   // needs (2*256*64 + 512) * 4 = 133 KB

  crf_scan_kernel<<<2 * NB, 64, 0, stream>>>(feats, trans, mask, ws);
  crf_combine_kernel<<<NB, 64, 0, stream>>>(feats, trans, tags, mask, ws, out);
}